// Round 3
// baseline (1311.043 us; speedup 1.0000x reference)
//
#include <hip/hip_runtime.h>
#include <cstddef>
#include <cstdint>

typedef _Float16 h4 __attribute__((ext_vector_type(4)));
typedef _Float16 h8 __attribute__((ext_vector_type(8)));
typedef float    f4 __attribute__((ext_vector_type(4)));

#define NN      50000
#define IND     512
#define HIDN    256
#define E2P     400000
#define EDD     800000

// ---- workspace layout (bytes) ----
#define OFF_HF16    ((size_t)0)            // 25,600,000  f16 h [NN][256]
#define OFF_LOGPHI  ((size_t)25600000)     //  1,600,000  f32 [NN][8]
#define OFF_DEG     ((size_t)27200000)     //    200,000  int [NN]
#define OFF_LOGDEG  ((size_t)27400000)     //    200,000  f32
#define OFF_DEGC    ((size_t)27600000)     //    200,000  f32
#define OFF_WT      ((size_t)27800000)     //    262,144  f16 enc_w1^T [256][512]
#define OFF_BT      ((size_t)28062144)     //     69,632  f16 edge_w1 perm^T [64][544]
#define OFF_RS      ((size_t)28131776)     //        512  f32 Rs[64] + alpha at [64]
#define OFF_WSYM    ((size_t)28132288)     //  1,600,000  f32 [E2P]
#define OFF_ENORM   ((size_t)29732288)     //  1,600,000  f32 [E2P]
#define OFF_MA      ((size_t)31332288)     // 12,800,000  f16 [EDD][8]
#define OFF_MB      ((size_t)44132288)     // 12,800,000
#define OFF_SA      ((size_t)56932288)     //  1,600,000  f32 [NN][8]
#define OFF_SB      ((size_t)58532288)     //  1,600,000
#define WS_NEED     ((size_t)60132288)

// ---------------- degree count ----------------
__global__ void k_deg(const int* __restrict__ ei, int* __restrict__ deg) {
    int e = blockIdx.x * 256 + threadIdx.x;   // grid exact: EDD
    atomicAdd(&deg[ei[e]], 1);
}

__global__ void k_node(const int* __restrict__ deg, float* __restrict__ logdeg,
                       float* __restrict__ degc) {
    int n = blockIdx.x * 256 + threadIdx.x;
    if (n < NN) {
        float d = (float)deg[n];
        logdeg[n] = logf(d + 1.0f);
        degc[n]   = fmaxf(d, 1.0f);
    }
}

// ---------------- weight prep ----------------
// Bt permutation: K-position kpos = kt*32 + q*8 + j  (kt<16, j = r*2+t):
//   orig feature = (t?256:0) + q*64 + kt*4 + r
// so that lane q's A-fragment over all kt reads h[q*64 .. q*64+63] contiguously.
__global__ void k_prep(const float* __restrict__ enc_w1, const float* __restrict__ edge_w1,
                       const float* __restrict__ R_raw, const float* __restrict__ Rsl,
                       const float* __restrict__ mlog,
                       _Float16* __restrict__ Wt, _Float16* __restrict__ Bt,
                       float* __restrict__ Rs) {
    int gid = blockIdx.x * 256 + threadIdx.x;
    if (gid < 256 * 512) {                       // Wt[n][k] = enc_w1[k][n]
        int n = gid >> 9, k = gid & 511;
        Wt[n * 512 + k] = (_Float16)enc_w1[k * 256 + n];
        return;
    }
    int g2 = gid - 256 * 512;
    if (g2 < 64 * 544) {
        int n = g2 / 544, kpos = g2 - n * 544;
        int kt = kpos >> 5, q = (kpos >> 3) & 3, j = kpos & 7;
        float v = 0.0f;
        if (kt < 16) {
            int r = j >> 1, t = j & 1;
            int orig = (t ? 256 : 0) + q * 64 + kt * 4 + r;
            v = edge_w1[orig * 64 + n];
        } else if (q == 0 && j < 2) {
            v = edge_w1[(512 + j) * 64 + n];
        }
        Bt[n * 544 + kpos] = (_Float16)v;
        return;
    }
    int g3 = g2 - 64 * 544;
    if (g3 < 64) {
        int c = g3 >> 3, d = g3 & 7;
        float rv = 0.5f * (R_raw[c * 8 + d] + R_raw[d * 8 + c]);
        float s  = log1pf(expf(Rsl[0])) + 1e-6f;
        Rs[g3] = s * tanhf(rv);
        return;
    }
    if (g3 == 64) {
        Rs[64] = 1.5f / (1.0f + expf(-mlog[0]));
    }
}

// ---------------- encoder layer 1: h = relu(x @ enc_w1 + b1), f16 MFMA ----------------
__global__ __launch_bounds__(256) void k_enc(const float* __restrict__ x,
                                             const _Float16* __restrict__ Wt,
                                             const float* __restrict__ b1,
                                             _Float16* __restrict__ hf) {
    __shared__ _Float16 XL[64 * 40];
    __shared__ _Float16 WL[256 * 40];
    const int tid = threadIdx.x;
    const int wid = tid >> 6;
    const int lane = tid & 63;
    const int l15 = lane & 15;
    const int q = lane >> 4;
    const int m0 = blockIdx.x * 64;

    f4 acc[16];
#pragma unroll
    for (int i = 0; i < 16; i++) acc[i] = (f4){0.f, 0.f, 0.f, 0.f};

    const int xr = tid >> 2;
    const int xs = tid & 3;
    const int gr = m0 + xr;

    for (int kt = 0; kt < 16; kt++) {
        __syncthreads();
        f4 xv0 = (f4){0, 0, 0, 0}, xv1 = (f4){0, 0, 0, 0};
        if (gr < NN) {
            const f4* xp = (const f4*)(x + (size_t)gr * IND + kt * 32 + xs * 8);
            xv0 = xp[0]; xv1 = xp[1];
        }
        h8 xh;
#pragma unroll
        for (int u = 0; u < 4; u++) { xh[u] = (_Float16)xv0[u]; xh[4 + u] = (_Float16)xv1[u]; }
        *(h8*)&XL[xr * 40 + xs * 8] = xh;
#pragma unroll
        for (int rep = 0; rep < 4; rep++) {
            int cid = rep * 256 + tid;
            int n = cid >> 2;
            int off = (cid & 3) * 8;
            h8 wv = *(const h8*)(Wt + (size_t)n * IND + kt * 32 + off);
            *(h8*)&WL[n * 40 + off] = wv;
        }
        __syncthreads();
        h8 a = *(const h8*)&XL[(wid * 16 + l15) * 40 + q * 8];
#pragma unroll
        for (int nt = 0; nt < 16; nt++) {
            h8 b = *(const h8*)&WL[(nt * 16 + l15) * 40 + q * 8];
            acc[nt] = __builtin_amdgcn_mfma_f32_16x16x32_f16(a, b, acc[nt], 0, 0, 0);
        }
    }
#pragma unroll
    for (int nt = 0; nt < 16; nt++) {
        int col = nt * 16 + l15;
        float bv = b1[col];
#pragma unroll
        for (int reg = 0; reg < 4; reg++) {
            int row = m0 + wid * 16 + q * 4 + reg;
            if (row < NN) {
                float v = acc[nt][reg] + bv;
                hf[(size_t)row * HIDN + col] = (_Float16)fmaxf(v, 0.f);
            }
        }
    }
}

// ---------------- encoder layer 2 + log_softmax ----------------
__global__ void k_logits(const _Float16* __restrict__ hf, const float* __restrict__ w2,
                         const float* __restrict__ b2, float* __restrict__ log_phi) {
    __shared__ float w2L[2048];
    for (int i = threadIdx.x; i < 2048; i += 256) w2L[i] = w2[i];
    __syncthreads();
    int n = blockIdx.x * 256 + threadIdx.x;
    if (n >= NN) return;
    float sum[8];
#pragma unroll
    for (int c = 0; c < 8; c++) sum[c] = b2[c];
    for (int kb = 0; kb < 32; kb++) {
        h8 hv = *(const h8*)(hf + (size_t)n * HIDN + kb * 8);
#pragma unroll
        for (int u = 0; u < 8; u++) {
            float hx = (float)hv[u];
            const float* wr = &w2L[(kb * 8 + u) * 8];
#pragma unroll
            for (int c = 0; c < 8; c++) sum[c] += hx * wr[c];
        }
    }
    float mx = sum[0];
#pragma unroll
    for (int c = 1; c < 8; c++) mx = fmaxf(mx, sum[c]);
    float se = 0.f;
#pragma unroll
    for (int c = 0; c < 8; c++) se += __expf(sum[c] - mx);
    float lse = __logf(se);
#pragma unroll
    for (int c = 0; c < 8; c++) log_phi[(size_t)n * 8 + c] = sum[c] - mx - lse;
}

// ---------------- edge MLP (pairs only), contiguous-h gathers ----------------
__global__ __launch_bounds__(256) void k_edge(const int* __restrict__ ei,
        const _Float16* __restrict__ hf, const float* __restrict__ logdeg,
        const _Float16* __restrict__ BtG, const float* __restrict__ eb1,
        const float* __restrict__ ew2, const float* __restrict__ eb2,
        float* __restrict__ wsym) {
    __shared__ _Float16 BtL[64 * 296];
    const int tid = threadIdx.x;
    const int wid = tid >> 6;
    const int lane = tid & 63;
    const int l15 = lane & 15;
    const int q = lane >> 4;
    const int eb = blockIdx.x * 256;

    int sidx[4], didx[4];
    float la[4], lb[4];
#pragma unroll
    for (int mt = 0; mt < 4; mt++) {
        int e = eb + wid * 64 + mt * 16 + l15;
        int ee = (e < E2P) ? e : 0;
        sidx[mt] = ei[ee];
        didx[mt] = ei[EDD + ee];
        la[mt] = logdeg[sidx[mt]];
        lb[mt] = logdeg[didx[mt]];
    }

    f4 acc[4][4];
#pragma unroll
    for (int a = 0; a < 4; a++)
#pragma unroll
        for (int b = 0; b < 4; b++) acc[a][b] = (f4){0.f, 0.f, 0.f, 0.f};

    for (int ph = 0; ph < 2; ph++) {
        const int kbase = ph ? 256 : 0;
        const int nch = ph ? 36 : 32;            // 8-half chunks per row this phase
        __syncthreads();
        {
            const int r = tid & 63;
            const int cb = tid >> 6;
            for (int ck = cb; ck < nch; ck += 4) {
                h8 v = *(const h8*)(BtG + (size_t)r * 544 + kbase + ck * 8);
                *(h8*)&BtL[r * 296 + ck * 8] = v;
            }
        }
        __syncthreads();
        const int kp0 = ph ? 4 : 0;
        const int kp1 = ph ? 8 : 4;
        for (int ktp = kp0; ktp < kp1; ktp++) {
            // batch-issue 8x16B gathers covering kt=2*ktp and 2*ktp+1
            h8 hs8[4], hd8[4];
#pragma unroll
            for (int mt = 0; mt < 4; mt++) {
                hs8[mt] = *(const h8*)(hf + (size_t)sidx[mt] * HIDN + q * 64 + ktp * 8);
                hd8[mt] = *(const h8*)(hf + (size_t)didx[mt] * HIDN + q * 64 + ktp * 8);
            }
#pragma unroll
            for (int half = 0; half < 2; half++) {
                const int kt = ktp * 2 + half;
                h8 af[4];
#pragma unroll
                for (int mt = 0; mt < 4; mt++) {
                    h8 a;
#pragma unroll
                    for (int u = 0; u < 4; u++) {
                        float x1 = (float)hs8[mt][half * 4 + u];
                        float x2 = (float)hd8[mt][half * 4 + u];
                        a[2 * u]     = (_Float16)(x1 * x2);
                        a[2 * u + 1] = (_Float16)fabsf(x1 - x2);
                    }
                    af[mt] = a;
                }
                const int ko = kt * 32 - kbase + q * 8;
                h8 bf[4];
#pragma unroll
                for (int nt = 0; nt < 4; nt++)
                    bf[nt] = *(const h8*)&BtL[(nt * 16 + l15) * 296 + ko];
#pragma unroll
                for (int mt = 0; mt < 4; mt++)
#pragma unroll
                    for (int nt = 0; nt < 4; nt++)
                        acc[mt][nt] = __builtin_amdgcn_mfma_f32_16x16x32_f16(af[mt], bf[nt], acc[mt][nt], 0, 0, 0);
            }
        }
    }
    // struct features kt=16 (cols 512..543, staged in phase1 at offset 256)
    {
        h8 bf[4];
#pragma unroll
        for (int nt = 0; nt < 4; nt++)
            bf[nt] = *(const h8*)&BtL[(nt * 16 + l15) * 296 + 256 + q * 8];
#pragma unroll
        for (int mt = 0; mt < 4; mt++) {
            h8 a = (h8){0, 0, 0, 0, 0, 0, 0, 0};
            if (q == 0) {
                a[0] = (_Float16)(la[mt] + lb[mt]);
                a[1] = (_Float16)fabsf(la[mt] - lb[mt]);
            }
#pragma unroll
            for (int nt = 0; nt < 4; nt++)
                acc[mt][nt] = __builtin_amdgcn_mfma_f32_16x16x32_f16(a, bf[nt], acc[mt][nt], 0, 0, 0);
        }
    }

    float b1v[4], w2v[4];
#pragma unroll
    for (int nt = 0; nt < 4; nt++) {
        int col = nt * 16 + l15;
        b1v[nt] = eb1[col];
        w2v[nt] = ew2[col];
    }
    const float b2s = eb2[0];
    float part[4][4];
#pragma unroll
    for (int mt = 0; mt < 4; mt++)
#pragma unroll
        for (int reg = 0; reg < 4; reg++) {
            float s = 0.f;
#pragma unroll
            for (int nt = 0; nt < 4; nt++) {
                float v = acc[mt][nt][reg] + b1v[nt];
                s += fmaxf(v, 0.f) * w2v[nt];
            }
            part[mt][reg] = s;
        }
#pragma unroll
    for (int off = 1; off < 16; off <<= 1)
#pragma unroll
        for (int mt = 0; mt < 4; mt++)
#pragma unroll
            for (int reg = 0; reg < 4; reg++)
                part[mt][reg] += __shfl_xor(part[mt][reg], off, 64);
    if (l15 == 0) {
#pragma unroll
        for (int mt = 0; mt < 4; mt++)
#pragma unroll
            for (int reg = 0; reg < 4; reg++) {
                int er = eb + wid * 64 + mt * 16 + q * 4 + reg;
                if (er < E2P) {
                    float xr = part[mt][reg] + b2s;
                    wsym[er] = 0.8f / (1.0f + __expf(-xr));
                }
            }
    }
}

// ======== BP: one thread per undirected pair, everything in registers ========

// fused m-init + first scatter (+ enorm)
__global__ __launch_bounds__(256) void k_init(const int* __restrict__ ei,
        const float* __restrict__ wsymb, const float* __restrict__ degc,
        const float* __restrict__ Rs, const float* __restrict__ log_phi,
        _Float16* __restrict__ m, float* __restrict__ enorm, float* __restrict__ S) {
    __shared__ float RsL[64];
    __shared__ float vals[256][16];
    __shared__ int   nds[256][2];
    const int tid = threadIdx.x;
    if (tid < 64) RsL[tid] = Rs[tid];
    __syncthreads();
    int p = blockIdx.x * 256 + tid;
    bool valid = p < E2P;
    int pe = valid ? p : 0;
    int sp = ei[pe], dp = ei[EDD + pe];
    float w = valid ? wsymb[pe] : 0.f;
    float nrm = valid ? rsqrtf(degc[sp] * degc[dp]) : 0.f;
    if (valid) enorm[p] = nrm;
    const f4* lpsp = (const f4*)(log_phi + (size_t)sp * 8);
    const f4* lpdp = (const f4*)(log_phi + (size_t)dp * 8);
    f4 ls0 = lpsp[0], ls1 = lpsp[1], ld0 = lpdp[0], ld1 = lpdp[1];
    float lps[8], lpd[8];
#pragma unroll
    for (int u = 0; u < 4; u++) { lps[u] = ls0[u]; lps[4+u] = ls1[u]; lpd[u] = ld0[u]; lpd[4+u] = ld1[u]; }
    // softmax in registers
    float me[8], mr[8];
    {
        float mx = lps[0], mx2 = lpd[0];
#pragma unroll
        for (int d = 1; d < 8; d++) { mx = fmaxf(mx, lps[d]); mx2 = fmaxf(mx2, lpd[d]); }
        float s = 0.f, s2 = 0.f;
#pragma unroll
        for (int d = 0; d < 8; d++) { me[d] = __expf(lps[d] - mx); s += me[d];
                                      mr[d] = __expf(lpd[d] - mx2); s2 += mr[d]; }
        float rs = 1.f / s, rs2 = 1.f / s2;
#pragma unroll
        for (int d = 0; d < 8; d++) { me[d] *= rs; mr[d] *= rs2; }
    }
    if (valid) {
        h8 mh, mh2;
#pragma unroll
        for (int d = 0; d < 8; d++) { mh[d] = (_Float16)me[d]; mh2[d] = (_Float16)mr[d]; }
        *(h8*)(m + (size_t)p * 8) = mh;
        *(h8*)(m + (size_t)(E2P + p) * 8) = mh2;
    }
    float fe[8], fr[8];
#pragma unroll
    for (int d = 0; d < 8; d++) { fe[d] = 0.f; fr[d] = 0.f; }
#pragma unroll
    for (int c = 0; c < 8; c++) {
#pragma unroll
        for (int d = 0; d < 8; d++) {
            float kv = __expf(w * RsL[c * 8 + d]);
            fe[d] += me[c] * kv;
            fr[d] += mr[c] * kv;
        }
    }
#pragma unroll
    for (int d = 0; d < 8; d++) {
        vals[tid][d]     = __logf(fmaxf(fe[d], 1e-12f)) * nrm;  // -> dst
        vals[tid][8 + d] = __logf(fmaxf(fr[d], 1e-12f)) * nrm;  // -> src
    }
    nds[tid][0] = valid ? dp : 0;
    nds[tid][1] = valid ? sp : 0;
    __syncthreads();
#pragma unroll
    for (int rep = 0; rep < 16; rep++) {
        int idx = rep * 256 + tid;
        int pl = idx >> 4, slot = idx & 15;
        int node = nds[pl][slot >> 3];
        atomicAdd(&S[(size_t)node * 8 + (slot & 7)], vals[pl][slot]);
    }
}

// fused BP step: new m + scatter of new log_f into Sn
__global__ __launch_bounds__(256) void k_bpF(const int* __restrict__ ei,
        const float* __restrict__ wsymb, const float* __restrict__ enorm,
        const float* __restrict__ Rs, const float* __restrict__ log_phi,
        const _Float16* __restrict__ m, const float* __restrict__ S,
        _Float16* __restrict__ mo, float* __restrict__ Sn) {
    __shared__ float RsL[64];
    __shared__ float vals[256][16];
    __shared__ int   nds[256][2];
    const int tid = threadIdx.x;
    if (tid < 64) RsL[tid] = Rs[tid];
    __syncthreads();
    int p = blockIdx.x * 256 + tid;
    bool valid = p < E2P;
    int pe = valid ? p : 0;
    int sp = ei[pe], dp = ei[EDD + pe];
    float w = valid ? wsymb[pe] : 0.f;
    float nrm = valid ? enorm[pe] : 0.f;
    const float alpha = Rs[64];
    // load m (f16), both directions
    h8 mhe = *(const h8*)(m + (size_t)pe * 8);
    h8 mhr = *(const h8*)(m + (size_t)(E2P + pe) * 8);
    float me[8], mr[8];
#pragma unroll
    for (int d = 0; d < 8; d++) { me[d] = (float)mhe[d]; mr[d] = (float)mhr[d]; }
    // f = m @ K  (K = exp(w*R)), both directions share K
    float fe[8], fr[8];
#pragma unroll
    for (int d = 0; d < 8; d++) { fe[d] = 0.f; fr[d] = 0.f; }
#pragma unroll
    for (int c = 0; c < 8; c++) {
#pragma unroll
        for (int d = 0; d < 8; d++) {
            float kv = __expf(w * RsL[c * 8 + d]);
            fe[d] += me[c] * kv;
            fr[d] += mr[c] * kv;
        }
    }
    float lfe[8], lfr[8];
#pragma unroll
    for (int d = 0; d < 8; d++) {
        lfe[d] = __logf(fmaxf(fe[d], 1e-12f)) * nrm;
        lfr[d] = __logf(fmaxf(fr[d], 1e-12f)) * nrm;
    }
    const f4* lpsp = (const f4*)(log_phi + (size_t)sp * 8);
    const f4* lpdp = (const f4*)(log_phi + (size_t)dp * 8);
    const f4* Ssp  = (const f4*)(S + (size_t)sp * 8);
    const f4* Sdp  = (const f4*)(S + (size_t)dp * 8);
    f4 ls0 = lpsp[0], ls1 = lpsp[1], ld0 = lpdp[0], ld1 = lpdp[1];
    f4 ss0 = Ssp[0],  ss1 = Ssp[1],  sd0 = Sdp[0],  sd1 = Sdp[1];
    float te[8], tr[8];
#pragma unroll
    for (int u = 0; u < 4; u++) {
        te[u]     = ls0[u] + alpha * (ss0[u] - lfr[u]);
        te[4 + u] = ls1[u] + alpha * (ss1[u] - lfr[4 + u]);
        tr[u]     = ld0[u] + alpha * (sd0[u] - lfe[u]);
        tr[4 + u] = ld1[u] + alpha * (sd1[u] - lfe[4 + u]);
    }
    // softmax + damping + renorm, in registers
    float m1[8], m2[8];
    {
        float mx = te[0], mx2 = tr[0];
#pragma unroll
        for (int d = 1; d < 8; d++) { mx = fmaxf(mx, te[d]); mx2 = fmaxf(mx2, tr[d]); }
        float s = 0.f, s2 = 0.f;
#pragma unroll
        for (int d = 0; d < 8; d++) { m1[d] = __expf(te[d] - mx); s += m1[d];
                                      m2[d] = __expf(tr[d] - mx2); s2 += m2[d]; }
        float rs = 1.f / s, rs2 = 1.f / s2;
        float t1 = 0.f, t2 = 0.f;
#pragma unroll
        for (int d = 0; d < 8; d++) {
            m1[d] = fmaxf(0.8f * me[d] + 0.2f * m1[d] * rs, 1e-12f);  t1 += m1[d];
            m2[d] = fmaxf(0.8f * mr[d] + 0.2f * m2[d] * rs2, 1e-12f); t2 += m2[d];
        }
        float rt1 = 1.f / t1, rt2 = 1.f / t2;
#pragma unroll
        for (int d = 0; d < 8; d++) { m1[d] *= rt1; m2[d] *= rt2; }
    }
    if (valid) {
        h8 mh, mh2;
#pragma unroll
        for (int d = 0; d < 8; d++) { mh[d] = (_Float16)m1[d]; mh2[d] = (_Float16)m2[d]; }
        *(h8*)(mo + (size_t)p * 8) = mh;
        *(h8*)(mo + (size_t)(E2P + p) * 8) = mh2;
    }
    // scatter NEW log_f into Sn (fused next-iteration gather)
    float fe2[8], fr2[8];
#pragma unroll
    for (int d = 0; d < 8; d++) { fe2[d] = 0.f; fr2[d] = 0.f; }
#pragma unroll
    for (int c = 0; c < 8; c++) {
#pragma unroll
        for (int d = 0; d < 8; d++) {
            float kv = __expf(w * RsL[c * 8 + d]);
            fe2[d] += m1[c] * kv;
            fr2[d] += m2[c] * kv;
        }
    }
#pragma unroll
    for (int d = 0; d < 8; d++) {
        vals[tid][d]     = __logf(fmaxf(fe2[d], 1e-12f)) * nrm;
        vals[tid][8 + d] = __logf(fmaxf(fr2[d], 1e-12f)) * nrm;
    }
    nds[tid][0] = valid ? dp : 0;
    nds[tid][1] = valid ? sp : 0;
    __syncthreads();
#pragma unroll
    for (int rep = 0; rep < 16; rep++) {
        int idx = rep * 256 + tid;
        int pl = idx >> 4, slot = idx & 15;
        int node = nds[pl][slot >> 3];
        atomicAdd(&Sn[(size_t)node * 8 + (slot & 7)], vals[pl][slot]);
    }
}

// ---------------- beliefs = softmax(log_phi + alpha*sum_in) ----------------
__global__ void k_bel(const float* __restrict__ log_phi, const float* __restrict__ sum_in,
                      const float* __restrict__ Rs, float* __restrict__ out) {
    int tid = blockIdx.x * 256 + threadIdx.x;
    if (tid >= NN * 8) return;
    float alpha = Rs[64];
    float v = log_phi[tid] + alpha * sum_in[tid];
    float mx = v;
    mx = fmaxf(mx, __shfl_xor(mx, 1, 64));
    mx = fmaxf(mx, __shfl_xor(mx, 2, 64));
    mx = fmaxf(mx, __shfl_xor(mx, 4, 64));
    float ex = __expf(v - mx);
    float s = ex;
    s += __shfl_xor(s, 1, 64); s += __shfl_xor(s, 2, 64); s += __shfl_xor(s, 4, 64);
    out[tid] = ex / s;
}

extern "C" void kernel_launch(void* const* d_in, const int* in_sizes, int n_in,
                              void* d_out, int out_size, void* d_ws, size_t ws_size,
                              hipStream_t stream) {
    if (ws_size < WS_NEED) return;
    const float* x        = (const float*)d_in[0];
    const int*   ei       = (const int*)d_in[1];
    const float* enc_w1   = (const float*)d_in[3];
    const float* enc_b1   = (const float*)d_in[4];
    const float* enc_w2   = (const float*)d_in[5];
    const float* enc_b2   = (const float*)d_in[6];
    const float* edge_w1  = (const float*)d_in[7];
    const float* edge_b1  = (const float*)d_in[8];
    const float* edge_w2  = (const float*)d_in[9];
    const float* edge_b2  = (const float*)d_in[10];
    const float* R_raw    = (const float*)d_in[11];
    const float* Rsl      = (const float*)d_in[12];
    const float* mlog     = (const float*)d_in[13];

    char* ws = (char*)d_ws;
    _Float16* hf     = (_Float16*)(ws + OFF_HF16);
    float* log_phi   = (float*)(ws + OFF_LOGPHI);
    int*   deg       = (int*)  (ws + OFF_DEG);
    float* logdeg    = (float*)(ws + OFF_LOGDEG);
    float* degc      = (float*)(ws + OFF_DEGC);
    _Float16* Wt     = (_Float16*)(ws + OFF_WT);
    _Float16* Bt     = (_Float16*)(ws + OFF_BT);
    float* Rs        = (float*)(ws + OFF_RS);
    float* wsym      = (float*)(ws + OFF_WSYM);
    float* enorm     = (float*)(ws + OFF_ENORM);
    _Float16* mA     = (_Float16*)(ws + OFF_MA);
    _Float16* mB     = (_Float16*)(ws + OFF_MB);
    float* SA        = (float*)(ws + OFF_SA);
    float* SB        = (float*)(ws + OFF_SB);

    hipMemsetAsync(deg, 0, (size_t)NN * 4, stream);
    k_deg<<<dim3(EDD / 256), dim3(256), 0, stream>>>(ei, deg);
    k_node<<<dim3((NN + 255) / 256), dim3(256), 0, stream>>>(deg, logdeg, degc);
    k_prep<<<dim3((256 * 512 + 64 * 544 + 65 + 255) / 256), dim3(256), 0, stream>>>(
        enc_w1, edge_w1, R_raw, Rsl, mlog, Wt, Bt, Rs);
    k_enc<<<dim3((NN + 63) / 64), dim3(256), 0, stream>>>(x, Wt, enc_b1, hf);
    k_logits<<<dim3((NN + 255) / 256), dim3(256), 0, stream>>>(hf, enc_w2, enc_b2, log_phi);
    k_edge<<<dim3((E2P + 255) / 256), dim3(256), 0, stream>>>(ei, hf, logdeg, Bt, edge_b1,
                                                              edge_w2, edge_b2, wsym);
    hipMemsetAsync(SA, 0, (size_t)NN * 8 * 4, stream);
    k_init<<<dim3((E2P + 255) / 256), dim3(256), 0, stream>>>(ei, wsym, degc, Rs, log_phi,
                                                              mA, enorm, SA);
    _Float16* mc = mA; _Float16* mn = mB;
    float* Sc = SA; float* Sx = SB;
    for (int t = 0; t < 10; t++) {
        hipMemsetAsync(Sx, 0, (size_t)NN * 8 * 4, stream);
        k_bpF<<<dim3((E2P + 255) / 256), dim3(256), 0, stream>>>(ei, wsym, enorm, Rs,
                                                                 log_phi, mc, Sc, mn, Sx);
        _Float16* tm = mc; mc = mn; mn = tm;
        float* ts = Sc; Sc = Sx; Sx = ts;
    }
    k_bel<<<dim3((NN * 8 + 255) / 256), dim3(256), 0, stream>>>(log_phi, Sc, Rs,
                                                                (float*)d_out);
    (void)in_sizes; (void)n_in; (void)out_size;
}

// Round 4
// 923.450 us; speedup vs baseline: 1.4197x; 1.4197x over previous
//
#include <hip/hip_runtime.h>
#include <cstddef>
#include <cstdint>

typedef _Float16 h4 __attribute__((ext_vector_type(4)));
typedef _Float16 h8 __attribute__((ext_vector_type(8)));
typedef float    f4 __attribute__((ext_vector_type(4)));

#define NN      50000
#define IND     512
#define HIDN    256
#define E2P     400000
#define EDD     800000
#define NBLK    196   // ceil(NN/256)

// ---- workspace layout (bytes) ----
// logf (f16 [EDD][8] = 12.8MB) aliases hf (dead after k_edge)
#define OFF_HF16    ((size_t)0)            // 25,600,000  f16 h [NN][256]
#define OFF_LOGF    ((size_t)0)            // 12,800,000  f16 [EDD][8] (CSR order)
#define OFF_LOGPHI  ((size_t)25600000)     //  1,600,000  f32 [NN][8]
#define OFF_DEG     ((size_t)27200000)     //    200,000  int
#define OFF_LOGDEG  ((size_t)27400000)     //    200,000  f32
#define OFF_DEGC    ((size_t)27600000)     //    200,000  f32
#define OFF_BASE    ((size_t)27800000)     //    200,000  int (CSR exclusive scan)
#define OFF_CNT     ((size_t)28000000)     //    200,000  int (scan scratch / fill counters)
#define OFF_BLK     ((size_t)28200000)     //      4,096  int (scan block sums)
#define OFF_WT      ((size_t)28204096)     //    262,144  f16 enc_w1^T
#define OFF_BT      ((size_t)28466240)     //     69,632  f16 edge_w1 perm^T
#define OFF_RS      ((size_t)28535872)     //        512  f32 Rs[64] + alpha at [64]
#define OFF_WSYM    ((size_t)28536384)     //  1,600,000  f32 [E2P]
#define OFF_ENORM   ((size_t)30136384)     //  1,600,000  f32 [E2P]
#define OFF_POS     ((size_t)31736384)     //  3,200,000  int [EDD] CSR slot of each directed edge
#define OFF_MA      ((size_t)34936384)     // 12,800,000  f16 [EDD][8]
#define OFF_MB      ((size_t)47736384)     // 12,800,000
#define OFF_SA      ((size_t)60536384)     //  1,600,000  f32 [NN][8]
#define OFF_SB      ((size_t)62136384)     //  1,600,000
#define WS_NEED     ((size_t)63736384)

// ---------------- degree count ----------------
__global__ void k_deg(const int* __restrict__ ei, int* __restrict__ deg) {
    int e = blockIdx.x * 256 + threadIdx.x;   // grid exact: EDD
    atomicAdd(&deg[ei[e]], 1);
}

__global__ void k_node(const int* __restrict__ deg, float* __restrict__ logdeg,
                       float* __restrict__ degc) {
    int n = blockIdx.x * 256 + threadIdx.x;
    if (n < NN) {
        float d = (float)deg[n];
        logdeg[n] = logf(d + 1.0f);
        degc[n]   = fmaxf(d, 1.0f);
    }
}

// ---------------- CSR prefix-sum (3 tiny kernels) ----------------
__global__ void k_scan1(const int* __restrict__ deg, int* __restrict__ incl,
                        int* __restrict__ blk) {
    __shared__ int sm[256];
    int i = blockIdx.x * 256 + threadIdx.x;
    int v = (i < NN) ? deg[i] : 0;
    sm[threadIdx.x] = v;
    __syncthreads();
    for (int off = 1; off < 256; off <<= 1) {
        int t = (threadIdx.x >= off) ? sm[threadIdx.x - off] : 0;
        __syncthreads();
        sm[threadIdx.x] += t;
        __syncthreads();
    }
    if (i < NN) incl[i] = sm[threadIdx.x];
    if (threadIdx.x == 255) blk[blockIdx.x] = sm[255];
}

__global__ void k_scan2(int* __restrict__ blk) {
    __shared__ int sm[256];
    int v = (threadIdx.x < NBLK) ? blk[threadIdx.x] : 0;
    sm[threadIdx.x] = v;
    __syncthreads();
    for (int off = 1; off < 256; off <<= 1) {
        int t = (threadIdx.x >= off) ? sm[threadIdx.x - off] : 0;
        __syncthreads();
        sm[threadIdx.x] += t;
        __syncthreads();
    }
    if (threadIdx.x < NBLK) blk[threadIdx.x] = sm[threadIdx.x];
}

__global__ void k_scan3(const int* __restrict__ incl, const int* __restrict__ deg,
                        const int* __restrict__ blk, int* __restrict__ base) {
    int i = blockIdx.x * 256 + threadIdx.x;
    if (i < NN) {
        int off = (blockIdx.x > 0) ? blk[blockIdx.x - 1] : 0;
        base[i] = off + incl[i] - deg[i];
    }
}

// pos[e] = CSR slot of directed edge e within its dst node's segment
__global__ void k_pos(const int* __restrict__ ei, const int* __restrict__ base,
                      int* __restrict__ cnt, int* __restrict__ pos) {
    int e = blockIdx.x * 256 + threadIdx.x;   // grid exact: EDD
    int dstn = ei[EDD + e];
    pos[e] = base[dstn] + atomicAdd(&cnt[dstn], 1);
}

// ---------------- weight prep (R2 interleaved-K perm for Bt) ----------------
__global__ void k_prep(const float* __restrict__ enc_w1, const float* __restrict__ edge_w1,
                       const float* __restrict__ R_raw, const float* __restrict__ Rsl,
                       const float* __restrict__ mlog,
                       _Float16* __restrict__ Wt, _Float16* __restrict__ Bt,
                       float* __restrict__ Rs) {
    int gid = blockIdx.x * 256 + threadIdx.x;
    if (gid < 256 * 512) {                       // Wt[n][k] = enc_w1[k][n]
        int n = gid >> 9, k = gid & 511;
        Wt[n * 512 + k] = (_Float16)enc_w1[k * 256 + n];
        return;
    }
    int g2 = gid - 256 * 512;
    if (g2 < 64 * 544) {                         // Bt[n][k'] with interleaved K perm
        int n = g2 / 544, k = g2 - n * 544;
        float v = 0.0f;
        if (k < 512) {
            int orig = (k & 1) ? 256 + (k >> 1) : (k >> 1);
            v = edge_w1[orig * 64 + n];
        } else if (k < 514) {
            v = edge_w1[k * 64 + n];
        }
        Bt[n * 544 + k] = (_Float16)v;
        return;
    }
    int g3 = g2 - 64 * 544;
    if (g3 < 64) {
        int c = g3 >> 3, d = g3 & 7;
        float rv = 0.5f * (R_raw[c * 8 + d] + R_raw[d * 8 + c]);
        float s  = log1pf(expf(Rsl[0])) + 1e-6f;
        Rs[g3] = s * tanhf(rv);
        return;
    }
    if (g3 == 64) {
        Rs[64] = 1.5f / (1.0f + expf(-mlog[0]));
    }
}

// ---------------- encoder layer 1: h = relu(x @ enc_w1 + b1), f16 MFMA ----------------
__global__ __launch_bounds__(256) void k_enc(const float* __restrict__ x,
                                             const _Float16* __restrict__ Wt,
                                             const float* __restrict__ b1,
                                             _Float16* __restrict__ hf) {
    __shared__ _Float16 XL[64 * 40];
    __shared__ _Float16 WL[256 * 40];
    const int tid = threadIdx.x;
    const int wid = tid >> 6;
    const int lane = tid & 63;
    const int l15 = lane & 15;
    const int q = lane >> 4;
    const int m0 = blockIdx.x * 64;

    f4 acc[16];
#pragma unroll
    for (int i = 0; i < 16; i++) acc[i] = (f4){0.f, 0.f, 0.f, 0.f};

    const int xr = tid >> 2;
    const int xs = tid & 3;
    const int gr = m0 + xr;

    for (int kt = 0; kt < 16; kt++) {
        __syncthreads();
        f4 xv0 = (f4){0, 0, 0, 0}, xv1 = (f4){0, 0, 0, 0};
        if (gr < NN) {
            const f4* xp = (const f4*)(x + (size_t)gr * IND + kt * 32 + xs * 8);
            xv0 = xp[0]; xv1 = xp[1];
        }
        h8 xh;
#pragma unroll
        for (int u = 0; u < 4; u++) { xh[u] = (_Float16)xv0[u]; xh[4 + u] = (_Float16)xv1[u]; }
        *(h8*)&XL[xr * 40 + xs * 8] = xh;
#pragma unroll
        for (int rep = 0; rep < 4; rep++) {
            int cid = rep * 256 + tid;
            int n = cid >> 2;
            int off = (cid & 3) * 8;
            h8 wv = *(const h8*)(Wt + (size_t)n * IND + kt * 32 + off);
            *(h8*)&WL[n * 40 + off] = wv;
        }
        __syncthreads();
        h8 a = *(const h8*)&XL[(wid * 16 + l15) * 40 + q * 8];
#pragma unroll
        for (int nt = 0; nt < 16; nt++) {
            h8 b = *(const h8*)&WL[(nt * 16 + l15) * 40 + q * 8];
            acc[nt] = __builtin_amdgcn_mfma_f32_16x16x32_f16(a, b, acc[nt], 0, 0, 0);
        }
    }
#pragma unroll
    for (int nt = 0; nt < 16; nt++) {
        int col = nt * 16 + l15;
        float bv = b1[col];
#pragma unroll
        for (int reg = 0; reg < 4; reg++) {
            int row = m0 + wid * 16 + q * 4 + reg;
            if (row < NN) {
                float v = acc[nt][reg] + bv;
                hf[(size_t)row * HIDN + col] = (_Float16)fmaxf(v, 0.f);
            }
        }
    }
}

// ---------------- encoder layer 2 + log_softmax ----------------
__global__ void k_logits(const _Float16* __restrict__ hf, const float* __restrict__ w2,
                         const float* __restrict__ b2, float* __restrict__ log_phi) {
    __shared__ float w2L[2048];
    for (int i = threadIdx.x; i < 2048; i += 256) w2L[i] = w2[i];
    __syncthreads();
    int n = blockIdx.x * 256 + threadIdx.x;
    if (n >= NN) return;
    float sum[8];
#pragma unroll
    for (int c = 0; c < 8; c++) sum[c] = b2[c];
    for (int kb = 0; kb < 32; kb++) {
        h8 hv = *(const h8*)(hf + (size_t)n * HIDN + kb * 8);
#pragma unroll
        for (int u = 0; u < 8; u++) {
            float hx = (float)hv[u];
            const float* wr = &w2L[(kb * 8 + u) * 8];
#pragma unroll
            for (int c = 0; c < 8; c++) sum[c] += hx * wr[c];
        }
    }
    float mx = sum[0];
#pragma unroll
    for (int c = 1; c < 8; c++) mx = fmaxf(mx, sum[c]);
    float se = 0.f;
#pragma unroll
    for (int c = 0; c < 8; c++) se += __expf(sum[c] - mx);
    float lse = __logf(se);
#pragma unroll
    for (int c = 0; c < 8; c++) log_phi[(size_t)n * 8 + c] = sum[c] - mx - lse;
}

// ---------------- edge MLP (pairs only), R2 gather pattern + 1-kt prefetch ----------------
__global__ __launch_bounds__(256) void k_edge(const int* __restrict__ ei,
        const _Float16* __restrict__ hf, const float* __restrict__ logdeg,
        const _Float16* __restrict__ BtG, const float* __restrict__ eb1,
        const float* __restrict__ ew2, const float* __restrict__ eb2,
        float* __restrict__ wsym) {
    __shared__ _Float16 BtL[64 * 168];
    const int tid = threadIdx.x;
    const int wid = tid >> 6;
    const int lane = tid & 63;
    const int l15 = lane & 15;
    const int q = lane >> 4;
    const int eb = blockIdx.x * 256;

    int sidx[4], didx[4];
    float la[4], lb[4];
#pragma unroll
    for (int mt = 0; mt < 4; mt++) {
        int e = eb + wid * 64 + mt * 16 + l15;
        int ee = (e < E2P) ? e : 0;
        sidx[mt] = ei[ee];
        didx[mt] = ei[EDD + ee];
        la[mt] = logdeg[sidx[mt]];
        lb[mt] = logdeg[didx[mt]];
    }

    f4 acc[4][4];
#pragma unroll
    for (int a = 0; a < 4; a++)
#pragma unroll
        for (int b = 0; b < 4; b++) acc[a][b] = (f4){0.f, 0.f, 0.f, 0.f};

    const _Float16* hq = hf + q * 4;
    h4 curS[4], curD[4];
#pragma unroll
    for (int mt = 0; mt < 4; mt++) {            // kt=0 fragments
        curS[mt] = *(const h4*)(hq + (size_t)sidx[mt] * HIDN);
        curD[mt] = *(const h4*)(hq + (size_t)didx[mt] * HIDN);
    }

    for (int ph = 0; ph < 4; ph++) {
        const int kbase = ph * 160;
        const int nch = (ph == 3) ? 8 : 20;
        __syncthreads();
        {
            const int r = tid & 63;
            const int cb = tid >> 6;
            for (int ck = cb; ck < nch; ck += 4) {
                h8 v = *(const h8*)(BtG + (size_t)r * 544 + kbase + ck * 8);
                *(h8*)&BtL[r * 168 + ck * 8] = v;
            }
        }
        __syncthreads();
        const int kt0 = ph * 5;
        const int kt1 = (ph == 3) ? 17 : kt0 + 5;
        for (int kt = kt0; kt < kt1; kt++) {
            h4 nxtS[4], nxtD[4];
            if (kt < 15) {                      // prefetch kt+1 gathers
                const int c1 = (kt + 1) * 16;
#pragma unroll
                for (int mt = 0; mt < 4; mt++) {
                    nxtS[mt] = *(const h4*)(hq + (size_t)sidx[mt] * HIDN + c1);
                    nxtD[mt] = *(const h4*)(hq + (size_t)didx[mt] * HIDN + c1);
                }
            }
            h8 af[4];
            if (kt < 16) {
#pragma unroll
                for (int mt = 0; mt < 4; mt++) {
                    h8 a;
#pragma unroll
                    for (int u = 0; u < 4; u++) {
                        float x1 = (float)curS[mt][u], x2 = (float)curD[mt][u];
                        a[2 * u]     = (_Float16)(x1 * x2);
                        a[2 * u + 1] = (_Float16)fabsf(x1 - x2);
                    }
                    af[mt] = a;
                }
            } else {
#pragma unroll
                for (int mt = 0; mt < 4; mt++) {
                    h8 a = (h8){0, 0, 0, 0, 0, 0, 0, 0};
                    if (q == 0) {
                        a[0] = (_Float16)(la[mt] + lb[mt]);
                        a[1] = (_Float16)fabsf(la[mt] - lb[mt]);
                    }
                    af[mt] = a;
                }
            }
            const int ko = kt * 32 - kbase + q * 8;
            h8 bf[4];
#pragma unroll
            for (int nt = 0; nt < 4; nt++)
                bf[nt] = *(const h8*)&BtL[(nt * 16 + l15) * 168 + ko];
#pragma unroll
            for (int mt = 0; mt < 4; mt++)
#pragma unroll
                for (int nt = 0; nt < 4; nt++)
                    acc[mt][nt] = __builtin_amdgcn_mfma_f32_16x16x32_f16(af[mt], bf[nt], acc[mt][nt], 0, 0, 0);
            if (kt < 15) {
#pragma unroll
                for (int mt = 0; mt < 4; mt++) { curS[mt] = nxtS[mt]; curD[mt] = nxtD[mt]; }
            }
        }
    }

    float b1v[4], w2v[4];
#pragma unroll
    for (int nt = 0; nt < 4; nt++) {
        int col = nt * 16 + l15;
        b1v[nt] = eb1[col];
        w2v[nt] = ew2[col];
    }
    const float b2s = eb2[0];
    float part[4][4];
#pragma unroll
    for (int mt = 0; mt < 4; mt++)
#pragma unroll
        for (int reg = 0; reg < 4; reg++) {
            float s = 0.f;
#pragma unroll
            for (int nt = 0; nt < 4; nt++) {
                float v = acc[mt][nt][reg] + b1v[nt];
                s += fmaxf(v, 0.f) * w2v[nt];
            }
            part[mt][reg] = s;
        }
#pragma unroll
    for (int off = 1; off < 16; off <<= 1)
#pragma unroll
        for (int mt = 0; mt < 4; mt++)
#pragma unroll
            for (int reg = 0; reg < 4; reg++)
                part[mt][reg] += __shfl_xor(part[mt][reg], off, 64);
    if (l15 == 0) {
#pragma unroll
        for (int mt = 0; mt < 4; mt++)
#pragma unroll
            for (int reg = 0; reg < 4; reg++) {
                int er = eb + wid * 64 + mt * 16 + q * 4 + reg;
                if (er < E2P) {
                    float xr = part[mt][reg] + b2s;
                    wsym[er] = 0.8f / (1.0f + __expf(-xr));
                }
            }
    }
}

// ======== BP: one thread per pair; no atomics — CSR-ordered log_f writes ========

__global__ __launch_bounds__(256) void k_init(const int* __restrict__ ei,
        const float* __restrict__ wsymb, const float* __restrict__ degc,
        const float* __restrict__ Rs, const float* __restrict__ log_phi,
        const int* __restrict__ pos, _Float16* __restrict__ m,
        float* __restrict__ enorm, _Float16* __restrict__ logf) {
    __shared__ float RsL[64];
    const int tid = threadIdx.x;
    if (tid < 64) RsL[tid] = Rs[tid];
    __syncthreads();
    int p = blockIdx.x * 256 + tid;
    if (p >= E2P) return;
    int sp = ei[p], dp = ei[EDD + p];
    float w = wsymb[p];
    float nrm = rsqrtf(degc[sp] * degc[dp]);
    enorm[p] = nrm;
    const f4* lpsp = (const f4*)(log_phi + (size_t)sp * 8);
    const f4* lpdp = (const f4*)(log_phi + (size_t)dp * 8);
    f4 ls0 = lpsp[0], ls1 = lpsp[1], ld0 = lpdp[0], ld1 = lpdp[1];
    float lps[8], lpd[8];
#pragma unroll
    for (int u = 0; u < 4; u++) { lps[u] = ls0[u]; lps[4+u] = ls1[u]; lpd[u] = ld0[u]; lpd[4+u] = ld1[u]; }
    float me[8], mr[8];
    {
        float mx = lps[0], mx2 = lpd[0];
#pragma unroll
        for (int d = 1; d < 8; d++) { mx = fmaxf(mx, lps[d]); mx2 = fmaxf(mx2, lpd[d]); }
        float s = 0.f, s2 = 0.f;
#pragma unroll
        for (int d = 0; d < 8; d++) { me[d] = __expf(lps[d] - mx); s += me[d];
                                      mr[d] = __expf(lpd[d] - mx2); s2 += mr[d]; }
        float rs = 1.f / s, rs2 = 1.f / s2;
#pragma unroll
        for (int d = 0; d < 8; d++) { me[d] *= rs; mr[d] *= rs2; }
    }
    {
        h8 mh, mh2;
#pragma unroll
        for (int d = 0; d < 8; d++) { mh[d] = (_Float16)me[d]; mh2[d] = (_Float16)mr[d]; }
        *(h8*)(m + (size_t)p * 8) = mh;
        *(h8*)(m + (size_t)(E2P + p) * 8) = mh2;
    }
    float fe[8], fr[8];
#pragma unroll
    for (int d = 0; d < 8; d++) { fe[d] = 0.f; fr[d] = 0.f; }
#pragma unroll
    for (int c = 0; c < 8; c++) {
#pragma unroll
        for (int d = 0; d < 8; d++) {
            float kv = __expf(w * RsL[c * 8 + d]);
            fe[d] += me[c] * kv;
            fr[d] += mr[c] * kv;
        }
    }
    h8 le, lr;
#pragma unroll
    for (int d = 0; d < 8; d++) {
        le[d] = (_Float16)(__logf(fmaxf(fe[d], 1e-12f)) * nrm);
        lr[d] = (_Float16)(__logf(fmaxf(fr[d], 1e-12f)) * nrm);
    }
    *(h8*)(logf + (size_t)pos[p] * 8)       = le;   // -> dp's segment
    *(h8*)(logf + (size_t)pos[E2P + p] * 8) = lr;   // -> sp's segment
}

// fused BP step: new m + CSR write of new log_f (no atomics)
__global__ __launch_bounds__(256) void k_bpF(const int* __restrict__ ei,
        const float* __restrict__ wsymb, const float* __restrict__ enorm,
        const float* __restrict__ Rs, const float* __restrict__ log_phi,
        const int* __restrict__ pos, const _Float16* __restrict__ m,
        const float* __restrict__ S, _Float16* __restrict__ mo,
        _Float16* __restrict__ logf) {
    __shared__ float RsL[64];
    const int tid = threadIdx.x;
    if (tid < 64) RsL[tid] = Rs[tid];
    __syncthreads();
    int p = blockIdx.x * 256 + tid;
    if (p >= E2P) return;
    int sp = ei[p], dp = ei[EDD + p];
    float w = wsymb[p], nrm = enorm[p];
    const float alpha = Rs[64];
    h8 mhe = *(const h8*)(m + (size_t)p * 8);
    h8 mhr = *(const h8*)(m + (size_t)(E2P + p) * 8);
    float me[8], mr[8];
#pragma unroll
    for (int d = 0; d < 8; d++) { me[d] = (float)mhe[d]; mr[d] = (float)mhr[d]; }
    float fe[8], fr[8];
#pragma unroll
    for (int d = 0; d < 8; d++) { fe[d] = 0.f; fr[d] = 0.f; }
#pragma unroll
    for (int c = 0; c < 8; c++) {
#pragma unroll
        for (int d = 0; d < 8; d++) {
            float kv = __expf(w * RsL[c * 8 + d]);
            fe[d] += me[c] * kv;
            fr[d] += mr[c] * kv;
        }
    }
    float lfe[8], lfr[8];
#pragma unroll
    for (int d = 0; d < 8; d++) {
        lfe[d] = __logf(fmaxf(fe[d], 1e-12f)) * nrm;
        lfr[d] = __logf(fmaxf(fr[d], 1e-12f)) * nrm;
    }
    const f4* lpsp = (const f4*)(log_phi + (size_t)sp * 8);
    const f4* lpdp = (const f4*)(log_phi + (size_t)dp * 8);
    const f4* Ssp  = (const f4*)(S + (size_t)sp * 8);
    const f4* Sdp  = (const f4*)(S + (size_t)dp * 8);
    f4 ls0 = lpsp[0], ls1 = lpsp[1], ld0 = lpdp[0], ld1 = lpdp[1];
    f4 ss0 = Ssp[0],  ss1 = Ssp[1],  sd0 = Sdp[0],  sd1 = Sdp[1];
    float te[8], tr[8];
#pragma unroll
    for (int u = 0; u < 4; u++) {
        te[u]     = ls0[u] + alpha * (ss0[u] - lfr[u]);
        te[4 + u] = ls1[u] + alpha * (ss1[u] - lfr[4 + u]);
        tr[u]     = ld0[u] + alpha * (sd0[u] - lfe[u]);
        tr[4 + u] = ld1[u] + alpha * (sd1[u] - lfe[4 + u]);
    }
    float m1[8], m2[8];
    {
        float mx = te[0], mx2 = tr[0];
#pragma unroll
        for (int d = 1; d < 8; d++) { mx = fmaxf(mx, te[d]); mx2 = fmaxf(mx2, tr[d]); }
        float s = 0.f, s2 = 0.f;
#pragma unroll
        for (int d = 0; d < 8; d++) { m1[d] = __expf(te[d] - mx); s += m1[d];
                                      m2[d] = __expf(tr[d] - mx2); s2 += m2[d]; }
        float rs = 1.f / s, rs2 = 1.f / s2;
        float t1 = 0.f, t2 = 0.f;
#pragma unroll
        for (int d = 0; d < 8; d++) {
            m1[d] = fmaxf(0.8f * me[d] + 0.2f * m1[d] * rs, 1e-12f);  t1 += m1[d];
            m2[d] = fmaxf(0.8f * mr[d] + 0.2f * m2[d] * rs2, 1e-12f); t2 += m2[d];
        }
        float rt1 = 1.f / t1, rt2 = 1.f / t2;
#pragma unroll
        for (int d = 0; d < 8; d++) { m1[d] *= rt1; m2[d] *= rt2; }
    }
    {
        h8 mh, mh2;
#pragma unroll
        for (int d = 0; d < 8; d++) { mh[d] = (_Float16)m1[d]; mh2[d] = (_Float16)m2[d]; }
        *(h8*)(mo + (size_t)p * 8) = mh;
        *(h8*)(mo + (size_t)(E2P + p) * 8) = mh2;
    }
    // new log_f for next iteration's sum
    float fe2[8], fr2[8];
#pragma unroll
    for (int d = 0; d < 8; d++) { fe2[d] = 0.f; fr2[d] = 0.f; }
#pragma unroll
    for (int c = 0; c < 8; c++) {
#pragma unroll
        for (int d = 0; d < 8; d++) {
            float kv = __expf(w * RsL[c * 8 + d]);
            fe2[d] += m1[c] * kv;
            fr2[d] += m2[c] * kv;
        }
    }
    h8 le, lr;
#pragma unroll
    for (int d = 0; d < 8; d++) {
        le[d] = (_Float16)(__logf(fmaxf(fe2[d], 1e-12f)) * nrm);
        lr[d] = (_Float16)(__logf(fmaxf(fr2[d], 1e-12f)) * nrm);
    }
    *(h8*)(logf + (size_t)pos[p] * 8)       = le;
    *(h8*)(logf + (size_t)pos[E2P + p] * 8) = lr;
}

// ---------------- sum_in: contiguous CSR reduction, no atomics ----------------
__global__ void k_sum(const _Float16* __restrict__ logf, const int* __restrict__ base,
                      const int* __restrict__ deg, float* __restrict__ S) {
    int tid = blockIdx.x * 256 + threadIdx.x;
    if (tid >= NN * 8) return;
    int n = tid >> 3, d = tid & 7;
    int b = base[n], cnt = deg[n];
    float s = 0.f;
    for (int j = 0; j < cnt; j++)
        s += (float)logf[(size_t)(b + j) * 8 + d];
    S[tid] = s;
}

// ---------------- beliefs = softmax(log_phi + alpha*sum_in) ----------------
__global__ void k_bel(const float* __restrict__ log_phi, const float* __restrict__ sum_in,
                      const float* __restrict__ Rs, float* __restrict__ out) {
    int tid = blockIdx.x * 256 + threadIdx.x;
    if (tid >= NN * 8) return;
    float alpha = Rs[64];
    float v = log_phi[tid] + alpha * sum_in[tid];
    float mx = v;
    mx = fmaxf(mx, __shfl_xor(mx, 1, 64));
    mx = fmaxf(mx, __shfl_xor(mx, 2, 64));
    mx = fmaxf(mx, __shfl_xor(mx, 4, 64));
    float ex = __expf(v - mx);
    float s = ex;
    s += __shfl_xor(s, 1, 64); s += __shfl_xor(s, 2, 64); s += __shfl_xor(s, 4, 64);
    out[tid] = ex / s;
}

extern "C" void kernel_launch(void* const* d_in, const int* in_sizes, int n_in,
                              void* d_out, int out_size, void* d_ws, size_t ws_size,
                              hipStream_t stream) {
    if (ws_size < WS_NEED) return;
    const float* x        = (const float*)d_in[0];
    const int*   ei       = (const int*)d_in[1];
    const float* enc_w1   = (const float*)d_in[3];
    const float* enc_b1   = (const float*)d_in[4];
    const float* enc_w2   = (const float*)d_in[5];
    const float* enc_b2   = (const float*)d_in[6];
    const float* edge_w1  = (const float*)d_in[7];
    const float* edge_b1  = (const float*)d_in[8];
    const float* edge_w2  = (const float*)d_in[9];
    const float* edge_b2  = (const float*)d_in[10];
    const float* R_raw    = (const float*)d_in[11];
    const float* Rsl      = (const float*)d_in[12];
    const float* mlog     = (const float*)d_in[13];

    char* ws = (char*)d_ws;
    _Float16* hf     = (_Float16*)(ws + OFF_HF16);
    _Float16* logfb  = (_Float16*)(ws + OFF_LOGF);
    float* log_phi   = (float*)(ws + OFF_LOGPHI);
    int*   deg       = (int*)  (ws + OFF_DEG);
    float* logdeg    = (float*)(ws + OFF_LOGDEG);
    float* degc      = (float*)(ws + OFF_DEGC);
    int*   baseA     = (int*)  (ws + OFF_BASE);
    int*   cnt       = (int*)  (ws + OFF_CNT);
    int*   blk       = (int*)  (ws + OFF_BLK);
    _Float16* Wt     = (_Float16*)(ws + OFF_WT);
    _Float16* Bt     = (_Float16*)(ws + OFF_BT);
    float* Rs        = (float*)(ws + OFF_RS);
    float* wsym      = (float*)(ws + OFF_WSYM);
    float* enorm     = (float*)(ws + OFF_ENORM);
    int*   pos       = (int*)  (ws + OFF_POS);
    _Float16* mA     = (_Float16*)(ws + OFF_MA);
    _Float16* mB     = (_Float16*)(ws + OFF_MB);
    float* SA        = (float*)(ws + OFF_SA);
    float* SB        = (float*)(ws + OFF_SB);

    hipMemsetAsync(deg, 0, (size_t)NN * 4, stream);
    k_deg<<<dim3(EDD / 256), dim3(256), 0, stream>>>(ei, deg);
    k_node<<<dim3(NBLK), dim3(256), 0, stream>>>(deg, logdeg, degc);
    k_prep<<<dim3((256 * 512 + 64 * 544 + 65 + 255) / 256), dim3(256), 0, stream>>>(
        enc_w1, edge_w1, R_raw, Rsl, mlog, Wt, Bt, Rs);
    // CSR build (one-time)
    k_scan1<<<dim3(NBLK), dim3(256), 0, stream>>>(deg, cnt /*incl scratch*/, blk);
    k_scan2<<<dim3(1), dim3(256), 0, stream>>>(blk);
    k_scan3<<<dim3(NBLK), dim3(256), 0, stream>>>(cnt, deg, blk, baseA);
    hipMemsetAsync(cnt, 0, (size_t)NN * 4, stream);
    k_pos<<<dim3(EDD / 256), dim3(256), 0, stream>>>(ei, baseA, cnt, pos);
    // encoder + edge MLP
    k_enc<<<dim3((NN + 63) / 64), dim3(256), 0, stream>>>(x, Wt, enc_b1, hf);
    k_logits<<<dim3(NBLK), dim3(256), 0, stream>>>(hf, enc_w2, enc_b2, log_phi);
    k_edge<<<dim3((E2P + 255) / 256), dim3(256), 0, stream>>>(ei, hf, logdeg, Bt, edge_b1,
                                                              edge_w2, edge_b2, wsym);
    // BP loop (logfb aliases hf — hf is dead from here on)
    k_init<<<dim3((E2P + 255) / 256), dim3(256), 0, stream>>>(ei, wsym, degc, Rs, log_phi,
                                                              pos, mA, enorm, logfb);
    k_sum<<<dim3((NN * 8 + 255) / 256), dim3(256), 0, stream>>>(logfb, baseA, deg, SA);
    _Float16* mc = mA; _Float16* mn = mB;
    float* Sc = SA; float* Sx = SB;
    for (int t = 0; t < 10; t++) {
        k_bpF<<<dim3((E2P + 255) / 256), dim3(256), 0, stream>>>(ei, wsym, enorm, Rs,
                                                                 log_phi, pos, mc, Sc, mn, logfb);
        k_sum<<<dim3((NN * 8 + 255) / 256), dim3(256), 0, stream>>>(logfb, baseA, deg, Sx);
        _Float16* tm = mc; mc = mn; mn = tm;
        float* ts = Sc; Sc = Sx; Sx = ts;
    }
    k_bel<<<dim3((NN * 8 + 255) / 256), dim3(256), 0, stream>>>(log_phi, Sc, Rs,
                                                                (float*)d_out);
    (void)in_sizes; (void)n_in; (void)out_size;
}